// Round 5
// baseline (701.615 us; speedup 1.0000x reference)
//
#include <hip/hip_runtime.h>
#include <math.h>

// Problem constants (DeformConv_68109591380935) — ALL TENSORS FLOAT32
#define BN_    4
#define CHI_   256
#define CHO_   256
#define HH_    96
#define WW_    96
#define HW_    (HH_*WW_)        // 9216
#define KK_    9
#define CK_    (CHI_*KK_)       // 2304
#define NRED_  (BN_*HW_)        // 36864 samples per BN channel
#define BN_EPS_ 1e-5f

// R5: deform path unfused into gather_cols (streaming, barrier-free) +
// cols_gemm (regular 128x128 MFMA GEMM). colsT[b][px 9216][k KP] bf16.
#define GTPX_  32               // pixels per gather block

// offset_mfma tiling: 32 oc (27 + 5 zero) x 64 px, KC 96 (UNCHANGED)
#define OTPX_   64
#define OKC_    96
#define OPITCH_ 104             // 208B rows (known-good class)

typedef short short8 __attribute__((ext_vector_type(8)));
typedef float f32x4  __attribute__((ext_vector_type(4)));

// round-to-nearest-even f32 -> bf16 bit pattern
__device__ __forceinline__ unsigned short f2bf(float v) {
    union { float f; unsigned u; } c; c.f = v;
    unsigned lsb = (c.u >> 16) & 1u;
    c.u += 0x7fffu + lsb;
    return (unsigned short)(c.u >> 16);
}

// ---------------------------------------------------------------------------
// Kernel 0: f32 -> bf16 convert (used for w_conv and w_offset)
// ---------------------------------------------------------------------------
__global__ __launch_bounds__(256) void w2b(
    const float* __restrict__ w, unsigned short* __restrict__ wb)
{
    int idx = blockIdx.x * 256 + threadIdx.x;
    wb[idx] = f2bf(w[idx]);
}

// ---------------------------------------------------------------------------
// Kernel 1: offset conv as MFMA GEMM (UNCHANGED from known-good baseline).
//   om[b, 27, HW] = Woff[27,2304] x im2col3x3(x)  + b_offset
// ---------------------------------------------------------------------------
__global__ __launch_bounds__(256) void offset_mfma(
    const float* __restrict__ x, const unsigned short* __restrict__ wob,
    const float* __restrict__ bo, float* __restrict__ om)
{
    __shared__ __align__(16) unsigned short s_w[32 * OPITCH_];     //  6656 B
    __shared__ __align__(16) unsigned short s_cols[OTPX_ * OPITCH_];// 13312 B

    const int t = threadIdx.x;
    const int pixtile = blockIdx.x % (HW_ / OTPX_);  // 144
    const int b       = blockIdx.x / (HW_ / OTPX_);  // 4
    const int p0 = pixtile * OTPX_;

    const int lane = t & 63, wave = t >> 6;
    const int quad = lane >> 4, l15 = lane & 15;

    const int i   = t & 63;            // pixel within tile (staging role)
    const int jlb = (t >> 6) * 24;     // k-subrange within chunk
    const int p   = p0 + i;
    const int h   = p / WW_, w = p % WW_;
    const float* xb = x + (size_t)b * CHI_ * HW_;

    f32x4 acc[2];
    acc[0] = (f32x4){0.f,0.f,0.f,0.f};
    acc[1] = (f32x4){0.f,0.f,0.f,0.f};

    for (int kc = 0; kc < CK_ / OKC_; kc++) {        // 24 chunks
        const int j0 = kc * OKC_;
        if (kc) __syncthreads();
        // ---- stage Woff chunk: 32 x 96 (rows >=27 zero), 3 uint2 per thread
#pragma unroll
        for (int n = 0; n < 3; n++) {
            int e = t + n * 256;                     // < 768
            int ocl = e / 24, kq = e % 24;
            uint2 v = make_uint2(0u, 0u);
            if (ocl < 27)
                v = *reinterpret_cast<const uint2*>(wob + (size_t)ocl * CK_ + j0 + kq * 4);
            *reinterpret_cast<uint2*>(&s_w[ocl * OPITCH_ + kq * 4]) = v;
        }
        // ---- stage im2col chunk: 96 k x 64 px, 24 per thread, 3x b128 write
        union { unsigned short s[24]; uint4 q[3]; } pk;
#pragma unroll
        for (int m = 0; m < 24; m++) {
            int jg = j0 + jlb + m;
            int c  = (jg * 7282) >> 16;              // jg/9
            int k  = jg - 9 * c;
            int yy = h + k / 3 - 1, xx = w + k % 3 - 1;
            bool ok = ((unsigned)yy < HH_) & ((unsigned)xx < WW_);
            float v = ok ? xb[(size_t)c * HW_ + yy * WW_ + xx] : 0.f;
            pk.s[m] = f2bf(v);
        }
        {
            uint4* dst = reinterpret_cast<uint4*>(&s_cols[i * OPITCH_ + jlb]);
            dst[0] = pk.q[0]; dst[1] = pk.q[1]; dst[2] = pk.q[2];
        }
        __syncthreads();
        // ---- MFMA: 3 K-steps, A = 2 oc-tiles, B = this wave's pixel quarter
#pragma unroll
        for (int ks = 0; ks < OKC_ / 32; ks++) {
            short8 a0 = *reinterpret_cast<const short8*>(
                &s_w[(l15) * OPITCH_ + ks * 32 + quad * 8]);
            short8 a1 = *reinterpret_cast<const short8*>(
                &s_w[(16 + l15) * OPITCH_ + ks * 32 + quad * 8]);
            short8 b0 = *reinterpret_cast<const short8*>(
                &s_cols[(wave * 16 + l15) * OPITCH_ + ks * 32 + quad * 8]);
            acc[0] = __builtin_amdgcn_mfma_f32_16x16x32_bf16(a0, b0, acc[0], 0, 0, 0);
            acc[1] = __builtin_amdgcn_mfma_f32_16x16x32_bf16(a1, b0, acc[1], 0, 0, 0);
        }
    }

    // epilogue: C/D layout col=lane&15 (pixel), row=quad*4+r (oc)
#pragma unroll
    for (int mt = 0; mt < 2; mt++) {
#pragma unroll
        for (int r = 0; r < 4; r++) {
            int oc = mt * 16 + quad * 4 + r;
            if (oc < 27) {
                int pix = p0 + wave * 16 + l15;
                om[((size_t)b * 27 + oc) * HW_ + pix] = acc[mt][r] + bo[oc];
            }
        }
    }
}

// ---------------------------------------------------------------------------
// Kernel 2a: streaming deformable gather -> colsT[b][px][k] bf16.
//   Block = 32 px; thread = 1 pixel x k-slice; NO barriers in main loop.
//   Covers k-range [k0, k0+KP).
// ---------------------------------------------------------------------------
__global__ __launch_bounds__(256) void gather_cols(
    const float* __restrict__ x, const float* __restrict__ om,
    unsigned short* __restrict__ cols, int k0, int KP)
{
    __shared__ float s_py[KK_ * GTPX_], s_px[KK_ * GTPX_], s_mask[KK_ * GTPX_];

    const int t = threadIdx.x;
    // XCD-aware: 1152 blocks = 8 XCDs x 144 contiguous (b,pxtile) units
    const int bid = blockIdx.x;
    const int j   = (bid & 7) * 144 + (bid >> 3);    // [0,1152)
    const int pixtile = j % (HW_ / GTPX_);           // 288
    const int b       = j / (HW_ / GTPX_);           // 4
    const int p0 = pixtile * GTPX_;

    // ---- meta: py/px/mask for 9 taps x 32 pixels ----
    for (int e = t; e < KK_ * GTPX_; e += 256) {
        int k = e >> 5, i = e & 31;
        int p = p0 + i;
        int h = p / WW_, w = p % WW_;
        const float* omb = om + ((size_t)b * 27) * HW_ + p;
        float dy = omb[(2 * k) * HW_];
        float dx = omb[(2 * k + 1) * HW_];
        float m  = omb[(18 + k) * HW_];
        s_py[e]   = dy + (float)(h + k / 3 - 1);
        s_px[e]   = dx + (float)(w + (k % 3) - 1);
        s_mask[e] = 1.f / (1.f + __expf(-m));
    }
    __syncthreads();

    const int ib    = t >> 3;          // local pixel 0..31
    const int kbase = (t & 7) * 8;     // k-offset within 64-stride groups
    const float* xb = x + (size_t)b * CHI_ * HW_;
    unsigned short* outp = cols + ((size_t)b * HW_ + (p0 + ib)) * KP;

    for (int m = 0; m < KP / 64; m++) {
        union { unsigned short s[8]; uint4 q; } pk;
#pragma unroll
        for (int u = 0; u < 8; u++) {
            int koff = kbase + m * 64 + u;
            int gk = k0 + koff;
            int c  = (gk * 7282) >> 16;           // gk/9 (valid < 9000)
            int k  = gk - 9 * c;
            float py = s_py[k * GTPX_ + ib], px = s_px[k * GTPX_ + ib];
            float y0f = floorf(py), x0f = floorf(px);
            float ly = py - y0f, lx = px - x0f;
            int y0 = (int)y0f, x0 = (int)x0f;
            float vy0 = ((unsigned)y0       < HH_) ? 1.f : 0.f;
            float vy1 = ((unsigned)(y0 + 1) < HH_) ? 1.f : 0.f;
            float vx0 = ((unsigned)x0       < WW_) ? 1.f : 0.f;
            float vx1 = ((unsigned)(x0 + 1) < WW_) ? 1.f : 0.f;
            int yc0 = min(max(y0, 0), HH_ - 1), yc1 = min(max(y0 + 1, 0), HH_ - 1);
            int xc0 = min(max(x0, 0), WW_ - 1), xc1 = min(max(x0 + 1, 0), WW_ - 1);
            const float* img = xb + (size_t)c * HW_;
            float f00 = img[yc0 * WW_ + xc0];
            float f01 = img[yc0 * WW_ + xc1];
            float f10 = img[yc1 * WW_ + xc0];
            float f11 = img[yc1 * WW_ + xc1];
            float wy0 = 1.f - ly, wx0 = 1.f - lx;
            float v = f00 * (wy0 * wx0 * vy0 * vx0) + f01 * (wy0 * lx * vy0 * vx1)
                    + f10 * (ly  * wx0 * vy1 * vx0) + f11 * (ly  * lx * vy1 * vx1);
            pk.s[u] = f2bf(v * s_mask[k * GTPX_ + ib]);
        }
        *reinterpret_cast<uint4*>(outp + kbase + m * 64) = pk.q;
    }
}

// ---------------------------------------------------------------------------
// Kernel 2b: regular bf16 MFMA GEMM over staged cols.
//   outb[b,oc,px] (+)= W[oc, k0:k0+KP] x colsT[b, px, 0:KP]
//   128x128 tile, 4 waves (2x2 quadrants), XOR-swizzled LDS (R3-proven).
// ---------------------------------------------------------------------------
__global__ __launch_bounds__(256, 3) void cols_gemm(
    const unsigned short* __restrict__ wbf,
    const unsigned short* __restrict__ cols,
    const float* __restrict__ bconv,
    float* __restrict__ outb, int k0, int KP, int addprev)
{
    __shared__ __align__(16) unsigned short sA[128 * 64];  // 16384 B
    __shared__ __align__(16) unsigned short sB[128 * 64];  // 16384 B

    const int t = threadIdx.x;
    // XCD swizzle: 576 blocks = 8 x 72
    const int bid = blockIdx.x;
    const int j = (bid & 7) * 72 + (bid >> 3);       // [0,576)
    const int nt  = j % 72;
    const int mtb = j / 72;                          // [0,8)
    const int mt  = mtb & 1, b = mtb >> 1;
    const int m0 = mt * 128, n0 = nt * 128;

    const int lane = t & 63, wave = t >> 6;
    const int quad = lane >> 4, l15 = lane & 15;
    const int wr = wave >> 1, wc = wave & 1;

    const int srow = t >> 3;                         // 0..31
    const int sko  = t & 7;                          // 0..7
    const unsigned short* colsb = cols + (size_t)b * HW_ * KP;

    f32x4 acc[4][4];
#pragma unroll
    for (int m = 0; m < 4; m++)
#pragma unroll
        for (int n = 0; n < 4; n++)
            acc[m][n] = (f32x4){0.f, 0.f, 0.f, 0.f};

    char* sAb = (char*)sA;
    char* sBb = (char*)sB;

    for (int kc = 0; kc < KP / 64; kc++) {
        const int j0 = kc * 64;
        if (kc) __syncthreads();
        // ---- stage A (W) and B (cols): 128 rows x 64 k each, swizzled ----
#pragma unroll
        for (int n = 0; n < 4; n++) {
            int row = srow + n * 32;
            int woff = row * 128 + ((sko * 16) ^ ((row & 7) << 4));
            uint4 va = *reinterpret_cast<const uint4*>(
                wbf + (size_t)(m0 + row) * CK_ + k0 + j0 + sko * 8);
            *reinterpret_cast<uint4*>(sAb + woff) = va;
            uint4 vb = *reinterpret_cast<const uint4*>(
                colsb + (size_t)(n0 + row) * KP + j0 + sko * 8);
            *reinterpret_cast<uint4*>(sBb + woff) = vb;
        }
        __syncthreads();
        // ---- MFMA: 2 K-steps of 32; wave quadrant 64oc x 64px ----
#pragma unroll
        for (int ks = 0; ks < 2; ks++) {
            short8 afr[4], bfr[4];
#pragma unroll
            for (int m = 0; m < 4; m++) {
                int r = wr * 64 + m * 16 + l15;
                afr[m] = *reinterpret_cast<const short8*>(
                    sAb + r * 128 + (((ks << 6) + (quad << 4)) ^ ((r & 7) << 4)));
            }
#pragma unroll
            for (int n = 0; n < 4; n++) {
                int r = wc * 64 + n * 16 + l15;
                bfr[n] = *reinterpret_cast<const short8*>(
                    sBb + r * 128 + (((ks << 6) + (quad << 4)) ^ ((r & 7) << 4)));
            }
#pragma unroll
            for (int m = 0; m < 4; m++)
#pragma unroll
                for (int n = 0; n < 4; n++)
                    acc[m][n] = __builtin_amdgcn_mfma_f32_16x16x32_bf16(
                        afr[m], bfr[n], acc[m][n], 0, 0, 0);
        }
    }

    // ---- epilogue: first phase adds bias, later phases accumulate ----
#pragma unroll
    for (int m = 0; m < 4; m++) {
#pragma unroll
        for (int n = 0; n < 4; n++) {
#pragma unroll
            for (int r = 0; r < 4; r++) {
                int oc  = m0 + wr * 64 + m * 16 + quad * 4 + r;
                int px  = n0 + wc * 64 + n * 16 + l15;
                size_t idx = ((size_t)b * CHO_ + oc) * HW_ + px;
                float v = acc[m][n][r];
                v += addprev ? outb[idx] : bconv[oc];
                outb[idx] = v;
            }
        }
    }
}

// ---------------------------------------------------------------------------
// Kernel 3: BN statistics (sum, sumsq) per channel, deterministic two-pass
// ---------------------------------------------------------------------------
__global__ __launch_bounds__(256) void bn_stats(
    const float* __restrict__ outb, float* __restrict__ stats)
{
    int o = blockIdx.x, t = threadIdx.x;
    float s = 0.f, s2 = 0.f;
    for (int b = 0; b < BN_; b++) {
        const float* base = outb + ((size_t)b * CHO_ + o) * HW_;
        for (int p = t; p < HW_; p += 256) {
            float v = base[p];
            s += v; s2 += v * v;
        }
    }
#pragma unroll
    for (int off = 32; off > 0; off >>= 1) {
        s  += __shfl_down(s,  off, 64);
        s2 += __shfl_down(s2, off, 64);
    }
    __shared__ float rs[4], rs2[4];
    int lane = t & 63, wv = t >> 6;
    if (lane == 0) { rs[wv] = s; rs2[wv] = s2; }
    __syncthreads();
    if (t == 0) {
        stats[o]        = rs[0] + rs[1] + rs[2] + rs[3];
        stats[CHO_ + o] = rs2[0] + rs2[1] + rs2[2] + rs2[3];
    }
}

// ---------------------------------------------------------------------------
// Kernel 4: BN apply + ReLU, f32 out
// ---------------------------------------------------------------------------
__global__ __launch_bounds__(256) void bn_apply(
    const float* __restrict__ outb, const float* __restrict__ stats,
    const float* __restrict__ gamma, const float* __restrict__ beta,
    float* __restrict__ y)
{
    int idx = blockIdx.x * 256 + threadIdx.x;
    size_t i0 = (size_t)idx * 4;                  // < 9437184
    int o = (int)((i0 / HW_) % CHO_);
    float4 v = *reinterpret_cast<const float4*>(outb + i0);
    const float invN = 1.f / (float)NRED_;
    float mu  = stats[o] * invN;
    float var = stats[CHO_ + o] * invN - mu * mu;
    float inv = rsqrtf(var + BN_EPS_);
    float sc = gamma[o] * inv;
    float sh = beta[o] - mu * sc;
    float4 r;
    r.x = fmaxf(v.x * sc + sh, 0.f);
    r.y = fmaxf(v.y * sc + sh, 0.f);
    r.z = fmaxf(v.z * sc + sh, 0.f);
    r.w = fmaxf(v.w * sc + sh, 0.f);
    *reinterpret_cast<float4*>(y + i0) = r;
}

// ---------------------------------------------------------------------------
extern "C" void kernel_launch(void* const* d_in, const int* in_sizes, int n_in,
                              void* d_out, int out_size, void* d_ws, size_t ws_size,
                              hipStream_t stream)
{
    const float* x   = (const float*)d_in[0];
    const float* wof = (const float*)d_in[1];
    const float* bof = (const float*)d_in[2];
    const float* wcv = (const float*)d_in[3];
    const float* bcv = (const float*)d_in[4];
    const float* gam = (const float*)d_in[5];
    const float* bet = (const float*)d_in[6];
    float* y = (float*)d_out;

    char* ws = (char*)d_ws;
    float*          om    = (float*)ws;                                   // 3.98 MB
    float*          outb  = (float*)(ws + (size_t)4 * 1024 * 1024);       // 36 MB
    float*          stats = (float*)(ws + (size_t)40 * 1024 * 1024);      // 2 KB
    unsigned short* wbf   = (unsigned short*)(ws + (size_t)40 * 1024 * 1024 + 8192);            // 1.125 MB
    unsigned short* wob   = (unsigned short*)(ws + (size_t)40 * 1024 * 1024 + 8192 + 1179648);  // 121.5 KB
    unsigned short* cols  = (unsigned short*)(ws + (size_t)44 * 1024 * 1024);

    // choose K-phasing by available workspace for cols
    const size_t colsoff = (size_t)44 * 1024 * 1024;
    const size_t cfull   = (size_t)BN_ * HW_ * CK_ * 2;    // 162 MB
    int P;
    if      (ws_size >= colsoff + cfull)      P = 1;
    else if (ws_size >= colsoff + cfull / 4)  P = 4;
    else                                      P = 36;
    const int KP = CK_ / P;

    w2b<<<(CHO_ * CK_) / 256, 256, 0, stream>>>(wcv, wbf);        // 2304 blocks
    w2b<<<(27 * CK_) / 256, 256, 0, stream>>>(wof, wob);          // 243 blocks
    offset_mfma<<<BN_ * (HW_ / OTPX_), 256, 0, stream>>>(x, wob, bof, om);
    for (int q = 0; q < P; q++) {
        const int k0 = q * KP;
        gather_cols<<<BN_ * (HW_ / GTPX_), 256, 0, stream>>>(x, om, cols, k0, KP);
        cols_gemm<<<BN_ * 2 * (HW_ / 128), 256, 0, stream>>>(wbf, cols, bcv, outb, k0, KP, q);
    }
    bn_stats<<<CHO_, 256, 0, stream>>>(outb, stats);
    bn_apply<<<(BN_ * CHO_ * HW_) / (4 * 256), 256, 0, stream>>>(outb, stats, gam, bet, y);
}

// Round 6
// 417.716 us; speedup vs baseline: 1.6796x; 1.6796x over previous
//
#include <hip/hip_runtime.h>
#include <math.h>

// Problem constants (DeformConv_68109591380935) — ALL TENSORS FLOAT32
#define BN_    4
#define CHI_   256
#define CHO_   256
#define HH_    96
#define WW_    96
#define HW_    (HH_*WW_)        // 9216
#define KK_    9
#define CK_    (CHI_*KK_)       // 2304
#define NRED_  (BN_*HW_)        // 36864 samples per BN channel
#define BN_EPS_ 1e-5f

// R6: channels-last gather. x -> xt (NHWC); K-dim reordered kk = k*256+c;
// gather_nhwc loads 4 corner rows of 256 channels coalesced, applies the
// (channel-invariant) bilinear weights once per (px,k), writes cols bf16.
// cols_gemm (R5-proven 128x128 MFMA tile) consumes cols with permuted W.

// offset_mfma tiling: 32 oc (27 + 5 zero) x 64 px, KC 96 (UNCHANGED)
#define OTPX_   64
#define OKC_    96
#define OPITCH_ 104             // 208B rows (known-good class)

typedef short short8 __attribute__((ext_vector_type(8)));
typedef float f32x4  __attribute__((ext_vector_type(4)));

// round-to-nearest-even f32 -> bf16 bit pattern
__device__ __forceinline__ unsigned short f2bf(float v) {
    union { float f; unsigned u; } c; c.f = v;
    unsigned lsb = (c.u >> 16) & 1u;
    c.u += 0x7fffu + lsb;
    return (unsigned short)(c.u >> 16);
}

// ---------------------------------------------------------------------------
// Kernel 0a: w_conv f32 -> bf16 with K-dim permutation (c,k) -> (k,c).
//   wb2[o][k*256 + c] = bf16(w[o][c*9 + k])
// ---------------------------------------------------------------------------
__global__ __launch_bounds__(256) void w2b_perm(
    const float* __restrict__ w, unsigned short* __restrict__ wb)
{
    int idx = blockIdx.x * 256 + threadIdx.x;     // o*2304 + k*256 + c
    int o  = idx / CK_;
    int kk = idx - o * CK_;
    int k  = kk >> 8;
    int c  = kk & 255;
    wb[idx] = f2bf(w[o * CK_ + c * KK_ + k]);
}

// ---------------------------------------------------------------------------
// Kernel 0b: plain f32 -> bf16 convert (w_offset)
// ---------------------------------------------------------------------------
__global__ __launch_bounds__(256) void w2b(
    const float* __restrict__ w, unsigned short* __restrict__ wb)
{
    int idx = blockIdx.x * 256 + threadIdx.x;
    wb[idx] = f2bf(w[idx]);
}

// ---------------------------------------------------------------------------
// Kernel 0c: NCHW -> NHWC transpose of x.  xt[b][p][c] = x[b][c][p]
//   Block: 64 ch x 64 px tile via LDS. 2304 blocks.
// ---------------------------------------------------------------------------
__global__ __launch_bounds__(256) void transpose_x(
    const float* __restrict__ x, float* __restrict__ xt)
{
    __shared__ float tile[64][65];
    const int t = threadIdx.x;
    const int bid = blockIdx.x;
    const int b  = bid / (144 * 4);
    const int r  = bid - b * 576;
    const int pt = r >> 2, ct = r & 3;
    const int p0 = pt * 64, c0 = ct * 64;

    const int px = t & 63, g = t >> 6;
#pragma unroll
    for (int i = 0; i < 16; i++) {
        int cr = g + i * 4;
        tile[cr][px] = x[((size_t)b * CHI_ + c0 + cr) * HW_ + p0 + px];
    }
    __syncthreads();
    const int c = t & 63;
#pragma unroll
    for (int i = 0; i < 16; i++) {
        int pr = g + i * 4;
        xt[((size_t)b * HW_ + p0 + pr) * CHI_ + c0 + c] = tile[c][pr];
    }
}

// ---------------------------------------------------------------------------
// Kernel 1: offset conv as MFMA GEMM (UNCHANGED from known-good baseline).
// ---------------------------------------------------------------------------
__global__ __launch_bounds__(256) void offset_mfma(
    const float* __restrict__ x, const unsigned short* __restrict__ wob,
    const float* __restrict__ bo, float* __restrict__ om)
{
    __shared__ __align__(16) unsigned short s_w[32 * OPITCH_];     //  6656 B
    __shared__ __align__(16) unsigned short s_cols[OTPX_ * OPITCH_];// 13312 B

    const int t = threadIdx.x;
    const int pixtile = blockIdx.x % (HW_ / OTPX_);  // 144
    const int b       = blockIdx.x / (HW_ / OTPX_);  // 4
    const int p0 = pixtile * OTPX_;

    const int lane = t & 63, wave = t >> 6;
    const int quad = lane >> 4, l15 = lane & 15;

    const int i   = t & 63;            // pixel within tile (staging role)
    const int jlb = (t >> 6) * 24;     // k-subrange within chunk
    const int p   = p0 + i;
    const int h   = p / WW_, w = p % WW_;
    const float* xb = x + (size_t)b * CHI_ * HW_;

    f32x4 acc[2];
    acc[0] = (f32x4){0.f,0.f,0.f,0.f};
    acc[1] = (f32x4){0.f,0.f,0.f,0.f};

    for (int kc = 0; kc < CK_ / OKC_; kc++) {        // 24 chunks
        const int j0 = kc * OKC_;
        if (kc) __syncthreads();
#pragma unroll
        for (int n = 0; n < 3; n++) {
            int e = t + n * 256;                     // < 768
            int ocl = e / 24, kq = e % 24;
            uint2 v = make_uint2(0u, 0u);
            if (ocl < 27)
                v = *reinterpret_cast<const uint2*>(wob + (size_t)ocl * CK_ + j0 + kq * 4);
            *reinterpret_cast<uint2*>(&s_w[ocl * OPITCH_ + kq * 4]) = v;
        }
        union { unsigned short s[24]; uint4 q[3]; } pk;
#pragma unroll
        for (int m = 0; m < 24; m++) {
            int jg = j0 + jlb + m;
            int c  = (jg * 7282) >> 16;              // jg/9
            int k  = jg - 9 * c;
            int yy = h + k / 3 - 1, xx = w + k % 3 - 1;
            bool ok = ((unsigned)yy < HH_) & ((unsigned)xx < WW_);
            float v = ok ? xb[(size_t)c * HW_ + yy * WW_ + xx] : 0.f;
            pk.s[m] = f2bf(v);
        }
        {
            uint4* dst = reinterpret_cast<uint4*>(&s_cols[i * OPITCH_ + jlb]);
            dst[0] = pk.q[0]; dst[1] = pk.q[1]; dst[2] = pk.q[2];
        }
        __syncthreads();
#pragma unroll
        for (int ks = 0; ks < OKC_ / 32; ks++) {
            short8 a0 = *reinterpret_cast<const short8*>(
                &s_w[(l15) * OPITCH_ + ks * 32 + quad * 8]);
            short8 a1 = *reinterpret_cast<const short8*>(
                &s_w[(16 + l15) * OPITCH_ + ks * 32 + quad * 8]);
            short8 b0 = *reinterpret_cast<const short8*>(
                &s_cols[(wave * 16 + l15) * OPITCH_ + ks * 32 + quad * 8]);
            acc[0] = __builtin_amdgcn_mfma_f32_16x16x32_bf16(a0, b0, acc[0], 0, 0, 0);
            acc[1] = __builtin_amdgcn_mfma_f32_16x16x32_bf16(a1, b0, acc[1], 0, 0, 0);
        }
    }

#pragma unroll
    for (int mt = 0; mt < 2; mt++) {
#pragma unroll
        for (int r = 0; r < 4; r++) {
            int oc = mt * 16 + quad * 4 + r;
            if (oc < 27) {
                int pix = p0 + wave * 16 + l15;
                om[((size_t)b * 27 + oc) * HW_ + pix] = acc[mt][r] + bo[oc];
            }
        }
    }
}

// ---------------------------------------------------------------------------
// Kernel 2a: channels-last deformable gather.
//   cols[b][px][ (k-kq0)*256 + c ] = bf16( bilinear(xt[b], py,px) * mask )
//   Block = 16 px x nk taps; wave handles 4 px; lane l covers channels 4l..4l+3.
//   All loads/writes coalesced; meta broadcast from LDS (same addr per wave).
// ---------------------------------------------------------------------------
__global__ __launch_bounds__(256) void gather_nhwc(
    const float* __restrict__ xt, const float* __restrict__ om,
    unsigned short* __restrict__ cols, int kq0, int nk)
{
    __shared__ float s_py[16 * KK_], s_px[16 * KK_], s_mask[16 * KK_];

    const int t = threadIdx.x;
    // XCD-aware: 2304 blocks = 8 XCDs x 288 units; unit -> (b, contiguous tile)
    const int bid = blockIdx.x;
    const int u   = (bid & 7) * 288 + (bid >> 3);    // [0,2304)
    const int pixtile = u % (HW_ / 16);              // 576
    const int b       = u / (HW_ / 16);              // 4
    const int p0 = pixtile * 16;

    // ---- meta once per (px_l, kl): 16*nk entries ----
    const int KP = nk << 8;
    for (int e = t; e < 16 * nk; e += 256) {
        int px_l = e / nk, kl = e - px_l * nk;
        int k = kq0 + kl;
        int p = p0 + px_l;
        int h = p / WW_, w = p % WW_;
        const float* omb = om + ((size_t)b * 27) * HW_ + p;
        float dy = omb[(2 * k) * HW_];
        float dx = omb[(2 * k + 1) * HW_];
        float m  = omb[(18 + k) * HW_];
        s_py[e]   = dy + (float)(h + k / 3 - 1);
        s_px[e]   = dx + (float)(w + (k % 3) - 1);
        s_mask[e] = 1.f / (1.f + __expf(-m));
    }
    __syncthreads();

    const int lane = t & 63, wave = t >> 6;
    const float* xtb = xt + (size_t)b * HW_ * CHI_;

    for (int pi = 0; pi < 4; pi++) {
        const int px_l = wave * 4 + pi;
        unsigned short* outp = cols + ((size_t)b * HW_ + p0 + px_l) * KP;
        for (int kl = 0; kl < nk; kl++) {
            int e = px_l * nk + kl;
            float py = s_py[e], pxx = s_px[e], msk = s_mask[e];
            float y0f = floorf(py), x0f = floorf(pxx);
            float ly = py - y0f, lx = pxx - x0f;
            int y0 = (int)y0f, x0 = (int)x0f;
            float vy0 = ((unsigned)y0       < HH_) ? 1.f : 0.f;
            float vy1 = ((unsigned)(y0 + 1) < HH_) ? 1.f : 0.f;
            float vx0 = ((unsigned)x0       < WW_) ? 1.f : 0.f;
            float vx1 = ((unsigned)(x0 + 1) < WW_) ? 1.f : 0.f;
            int yc0 = min(max(y0, 0), HH_ - 1), yc1 = min(max(y0 + 1, 0), HH_ - 1);
            int xc0 = min(max(x0, 0), WW_ - 1), xc1 = min(max(x0 + 1, 0), WW_ - 1);
            float wy0 = 1.f - ly, wx0 = 1.f - lx;
            float w00 = wy0 * wx0 * vy0 * vx0 * msk;
            float w01 = wy0 * lx  * vy0 * vx1 * msk;
            float w10 = ly  * wx0 * vy1 * vx0 * msk;
            float w11 = ly  * lx  * vy1 * vx1 * msk;
            const float4 f00 = *reinterpret_cast<const float4*>(
                xtb + (size_t)(yc0 * WW_ + xc0) * CHI_ + 4 * lane);
            const float4 f01 = *reinterpret_cast<const float4*>(
                xtb + (size_t)(yc0 * WW_ + xc1) * CHI_ + 4 * lane);
            const float4 f10 = *reinterpret_cast<const float4*>(
                xtb + (size_t)(yc1 * WW_ + xc0) * CHI_ + 4 * lane);
            const float4 f11 = *reinterpret_cast<const float4*>(
                xtb + (size_t)(yc1 * WW_ + xc1) * CHI_ + 4 * lane);
            union { unsigned short s[4]; uint2 q; } pk;
            pk.s[0] = f2bf(f00.x * w00 + f01.x * w01 + f10.x * w10 + f11.x * w11);
            pk.s[1] = f2bf(f00.y * w00 + f01.y * w01 + f10.y * w10 + f11.y * w11);
            pk.s[2] = f2bf(f00.z * w00 + f01.z * w01 + f10.z * w10 + f11.z * w11);
            pk.s[3] = f2bf(f00.w * w00 + f01.w * w01 + f10.w * w10 + f11.w * w11);
            *reinterpret_cast<uint2*>(outp + (kl << 8) + 4 * lane) = pk.q;
        }
    }
}

// ---------------------------------------------------------------------------
// Kernel 2b: regular bf16 MFMA GEMM over staged cols (R5 structure).
//   outb[b,oc,px] (+)= W'[oc, k0:k0+KP] x cols[b, px, 0:KP]
// ---------------------------------------------------------------------------
__global__ __launch_bounds__(256, 3) void cols_gemm(
    const unsigned short* __restrict__ wbf,
    const unsigned short* __restrict__ cols,
    const float* __restrict__ bconv,
    float* __restrict__ outb, int k0, int KP, int addprev)
{
    __shared__ __align__(16) unsigned short sA[128 * 64];  // 16384 B
    __shared__ __align__(16) unsigned short sB[128 * 64];  // 16384 B

    const int t = threadIdx.x;
    const int bid = blockIdx.x;
    const int j = (bid & 7) * 72 + (bid >> 3);       // [0,576)
    const int nt  = j % 72;
    const int mtb = j / 72;                          // [0,8)
    const int mt  = mtb & 1, b = mtb >> 1;
    const int m0 = mt * 128, n0 = nt * 128;

    const int lane = t & 63, wave = t >> 6;
    const int quad = lane >> 4, l15 = lane & 15;
    const int wr = wave >> 1, wc = wave & 1;

    const int srow = t >> 3;                         // 0..31
    const int sko  = t & 7;                          // 0..7
    const unsigned short* colsb = cols + (size_t)b * HW_ * KP;

    f32x4 acc[4][4];
#pragma unroll
    for (int m = 0; m < 4; m++)
#pragma unroll
        for (int n = 0; n < 4; n++)
            acc[m][n] = (f32x4){0.f, 0.f, 0.f, 0.f};

    char* sAb = (char*)sA;
    char* sBb = (char*)sB;

    for (int kc = 0; kc < KP / 64; kc++) {
        const int j0 = kc * 64;
        if (kc) __syncthreads();
#pragma unroll
        for (int n = 0; n < 4; n++) {
            int row = srow + n * 32;
            int woff = row * 128 + ((sko * 16) ^ ((row & 7) << 4));
            uint4 va = *reinterpret_cast<const uint4*>(
                wbf + (size_t)(m0 + row) * CK_ + k0 + j0 + sko * 8);
            *reinterpret_cast<uint4*>(sAb + woff) = va;
            uint4 vb = *reinterpret_cast<const uint4*>(
                colsb + (size_t)(n0 + row) * KP + j0 + sko * 8);
            *reinterpret_cast<uint4*>(sBb + woff) = vb;
        }
        __syncthreads();
#pragma unroll
        for (int ks = 0; ks < 2; ks++) {
            short8 afr[4], bfr[4];
#pragma unroll
            for (int m = 0; m < 4; m++) {
                int r = wr * 64 + m * 16 + l15;
                afr[m] = *reinterpret_cast<const short8*>(
                    sAb + r * 128 + (((ks << 6) + (quad << 4)) ^ ((r & 7) << 4)));
            }
#pragma unroll
            for (int n = 0; n < 4; n++) {
                int r = wc * 64 + n * 16 + l15;
                bfr[n] = *reinterpret_cast<const short8*>(
                    sBb + r * 128 + (((ks << 6) + (quad << 4)) ^ ((r & 7) << 4)));
            }
#pragma unroll
            for (int m = 0; m < 4; m++)
#pragma unroll
                for (int n = 0; n < 4; n++)
                    acc[m][n] = __builtin_amdgcn_mfma_f32_16x16x32_bf16(
                        afr[m], bfr[n], acc[m][n], 0, 0, 0);
        }
    }

#pragma unroll
    for (int m = 0; m < 4; m++) {
#pragma unroll
        for (int n = 0; n < 4; n++) {
#pragma unroll
            for (int r = 0; r < 4; r++) {
                int oc  = m0 + wr * 64 + m * 16 + quad * 4 + r;
                int px  = n0 + wc * 64 + n * 16 + l15;
                size_t idx = ((size_t)b * CHO_ + oc) * HW_ + px;
                float v = acc[m][n][r];
                v += addprev ? outb[idx] : bconv[oc];
                outb[idx] = v;
            }
        }
    }
}

// ---------------------------------------------------------------------------
// Kernel 3: BN statistics (sum, sumsq) per channel, deterministic two-pass
// ---------------------------------------------------------------------------
__global__ __launch_bounds__(256) void bn_stats(
    const float* __restrict__ outb, float* __restrict__ stats)
{
    int o = blockIdx.x, t = threadIdx.x;
    float s = 0.f, s2 = 0.f;
    for (int b = 0; b < BN_; b++) {
        const float* base = outb + ((size_t)b * CHO_ + o) * HW_;
        for (int p = t; p < HW_; p += 256) {
            float v = base[p];
            s += v; s2 += v * v;
        }
    }
#pragma unroll
    for (int off = 32; off > 0; off >>= 1) {
        s  += __shfl_down(s,  off, 64);
        s2 += __shfl_down(s2, off, 64);
    }
    __shared__ float rs[4], rs2[4];
    int lane = t & 63, wv = t >> 6;
    if (lane == 0) { rs[wv] = s; rs2[wv] = s2; }
    __syncthreads();
    if (t == 0) {
        stats[o]        = rs[0] + rs[1] + rs[2] + rs[3];
        stats[CHO_ + o] = rs2[0] + rs2[1] + rs2[2] + rs2[3];
    }
}

// ---------------------------------------------------------------------------
// Kernel 4: BN apply + ReLU, f32 out
// ---------------------------------------------------------------------------
__global__ __launch_bounds__(256) void bn_apply(
    const float* __restrict__ outb, const float* __restrict__ stats,
    const float* __restrict__ gamma, const float* __restrict__ beta,
    float* __restrict__ y)
{
    int idx = blockIdx.x * 256 + threadIdx.x;
    size_t i0 = (size_t)idx * 4;                  // < 9437184
    int o = (int)((i0 / HW_) % CHO_);
    float4 v = *reinterpret_cast<const float4*>(outb + i0);
    const float invN = 1.f / (float)NRED_;
    float mu  = stats[o] * invN;
    float var = stats[CHO_ + o] * invN - mu * mu;
    float inv = rsqrtf(var + BN_EPS_);
    float sc = gamma[o] * inv;
    float sh = beta[o] - mu * sc;
    float4 r;
    r.x = fmaxf(v.x * sc + sh, 0.f);
    r.y = fmaxf(v.y * sc + sh, 0.f);
    r.z = fmaxf(v.z * sc + sh, 0.f);
    r.w = fmaxf(v.w * sc + sh, 0.f);
    *reinterpret_cast<float4*>(y + i0) = r;
}

// ---------------------------------------------------------------------------
extern "C" void kernel_launch(void* const* d_in, const int* in_sizes, int n_in,
                              void* d_out, int out_size, void* d_ws, size_t ws_size,
                              hipStream_t stream)
{
    const float* x   = (const float*)d_in[0];
    const float* wof = (const float*)d_in[1];
    const float* bof = (const float*)d_in[2];
    const float* wcv = (const float*)d_in[3];
    const float* bcv = (const float*)d_in[4];
    const float* gam = (const float*)d_in[5];
    const float* bet = (const float*)d_in[6];
    float* y = (float*)d_out;

    char* ws = (char*)d_ws;
    float*          om    = (float*)ws;                                   // 3.98 MB
    float*          outb  = (float*)(ws + (size_t)4 * 1024 * 1024);       // 36 MB
    float*          stats = (float*)(ws + (size_t)40 * 1024 * 1024);      // 2 KB
    unsigned short* wbf2  = (unsigned short*)(ws + (size_t)40 * 1024 * 1024 + 8192);            // 1.125 MB
    unsigned short* wob   = (unsigned short*)(ws + (size_t)40 * 1024 * 1024 + 8192 + 1179648);  // 121.5 KB
    float*          xt    = (float*)(ws + (size_t)44 * 1024 * 1024);      // 37.75 MB
    unsigned short* cols  = (unsigned short*)(ws + (size_t)84 * 1024 * 1024);

    // K-phasing (on whole taps) by available workspace for cols
    const size_t colsoff = (size_t)84 * 1024 * 1024;
    const size_t cfull   = (size_t)BN_ * HW_ * CK_ * 2;    // 162 MB
    int nk;
    if      (ws_size >= colsoff + cfull)      nk = 9;
    else if (ws_size >= colsoff + cfull / 3)  nk = 3;
    else                                      nk = 1;
    const int P  = KK_ / nk;
    const int KP = nk * 256;

    w2b_perm<<<(CHO_ * CK_) / 256, 256, 0, stream>>>(wcv, wbf2);  // 2304 blocks
    w2b<<<(27 * CK_) / 256, 256, 0, stream>>>(wof, wob);          // 243 blocks
    transpose_x<<<BN_ * 144 * 4, 256, 0, stream>>>(x, xt);        // 2304 blocks
    offset_mfma<<<BN_ * (HW_ / OTPX_), 256, 0, stream>>>(x, wob, bof, om);
    for (int q = 0; q < P; q++) {
        gather_nhwc<<<BN_ * (HW_ / 16), 256, 0, stream>>>(xt, om, cols, q * nk, nk);
        cols_gemm<<<BN_ * 2 * (HW_ / 128), 256, 0, stream>>>(
            wbf2, cols, bcv, outb, q * KP, KP, q);
    }
    bn_stats<<<CHO_, 256, 0, stream>>>(outb, stats);
    bn_apply<<<(BN_ * CHO_ * HW_) / (4 * 256), 256, 0, stream>>>(outb, stats, gam, bet, y);
}

// Round 7
// 392.178 us; speedup vs baseline: 1.7890x; 1.0651x over previous
//
#include <hip/hip_runtime.h>
#include <math.h>

// Problem constants (DeformConv_68109591380935) — ALL TENSORS FLOAT32
#define BN_    4
#define CHI_   256
#define CHO_   256
#define HH_    96
#define WW_    96
#define HW_    (HH_*WW_)        // 9216
#define KK_    9
#define CK_    (CHI_*KK_)       // 2304
#define NRED_  (BN_*HW_)        // 36864 samples per BN channel
#define BN_EPS_ 1e-5f

// R7: gather fused into GEMM B-stage. x -> xt (NHWC); W permuted kk=k*256+c;
// deform_fused: 256oc x 64px block, chunk = 1 tap x 64 ch; B-stage is a
// coalesced channels-last gather (R6-proven math), A/MFMA/epilogue = R3.

// offset_mfma tiling: 32 oc (27 + 5 zero) x 64 px, KC 96 (UNCHANGED)
#define OTPX_   64
#define OKC_    96
#define OPITCH_ 104             // 208B rows (known-good class)

typedef short short8 __attribute__((ext_vector_type(8)));
typedef float f32x4  __attribute__((ext_vector_type(4)));

// round-to-nearest-even f32 -> bf16 bit pattern
__device__ __forceinline__ unsigned short f2bf(float v) {
    union { float f; unsigned u; } c; c.f = v;
    unsigned lsb = (c.u >> 16) & 1u;
    c.u += 0x7fffu + lsb;
    return (unsigned short)(c.u >> 16);
}

// ---------------------------------------------------------------------------
// Kernel 0a: w_conv f32 -> bf16 with K-dim permutation (c,k) -> (k,c).
//   wb2[o][k*256 + c] = bf16(w[o][c*9 + k])
// ---------------------------------------------------------------------------
__global__ __launch_bounds__(256) void w2b_perm(
    const float* __restrict__ w, unsigned short* __restrict__ wb)
{
    int idx = blockIdx.x * 256 + threadIdx.x;     // o*2304 + k*256 + c
    int o  = idx / CK_;
    int kk = idx - o * CK_;
    int k  = kk >> 8;
    int c  = kk & 255;
    wb[idx] = f2bf(w[o * CK_ + c * KK_ + k]);
}

// ---------------------------------------------------------------------------
// Kernel 0b: plain f32 -> bf16 convert (w_offset)
// ---------------------------------------------------------------------------
__global__ __launch_bounds__(256) void w2b(
    const float* __restrict__ w, unsigned short* __restrict__ wb)
{
    int idx = blockIdx.x * 256 + threadIdx.x;
    wb[idx] = f2bf(w[idx]);
}

// ---------------------------------------------------------------------------
// Kernel 0c: NCHW -> NHWC transpose of x.  xt[b][p][c] = x[b][c][p]
// ---------------------------------------------------------------------------
__global__ __launch_bounds__(256) void transpose_x(
    const float* __restrict__ x, float* __restrict__ xt)
{
    __shared__ float tile[64][65];
    const int t = threadIdx.x;
    const int bid = blockIdx.x;
    const int b  = bid / (144 * 4);
    const int r  = bid - b * 576;
    const int pt = r >> 2, ct = r & 3;
    const int p0 = pt * 64, c0 = ct * 64;

    const int px = t & 63, g = t >> 6;
#pragma unroll
    for (int i = 0; i < 16; i++) {
        int cr = g + i * 4;
        tile[cr][px] = x[((size_t)b * CHI_ + c0 + cr) * HW_ + p0 + px];
    }
    __syncthreads();
    const int c = t & 63;
#pragma unroll
    for (int i = 0; i < 16; i++) {
        int pr = g + i * 4;
        xt[((size_t)b * HW_ + p0 + pr) * CHI_ + c0 + c] = tile[c][pr];
    }
}

// ---------------------------------------------------------------------------
// Kernel 1: offset conv as MFMA GEMM (UNCHANGED from known-good baseline).
// ---------------------------------------------------------------------------
__global__ __launch_bounds__(256) void offset_mfma(
    const float* __restrict__ x, const unsigned short* __restrict__ wob,
    const float* __restrict__ bo, float* __restrict__ om)
{
    __shared__ __align__(16) unsigned short s_w[32 * OPITCH_];     //  6656 B
    __shared__ __align__(16) unsigned short s_cols[OTPX_ * OPITCH_];// 13312 B

    const int t = threadIdx.x;
    const int pixtile = blockIdx.x % (HW_ / OTPX_);  // 144
    const int b       = blockIdx.x / (HW_ / OTPX_);  // 4
    const int p0 = pixtile * OTPX_;

    const int lane = t & 63, wave = t >> 6;
    const int quad = lane >> 4, l15 = lane & 15;

    const int i   = t & 63;            // pixel within tile (staging role)
    const int jlb = (t >> 6) * 24;     // k-subrange within chunk
    const int p   = p0 + i;
    const int h   = p / WW_, w = p % WW_;
    const float* xb = x + (size_t)b * CHI_ * HW_;

    f32x4 acc[2];
    acc[0] = (f32x4){0.f,0.f,0.f,0.f};
    acc[1] = (f32x4){0.f,0.f,0.f,0.f};

    for (int kc = 0; kc < CK_ / OKC_; kc++) {        // 24 chunks
        const int j0 = kc * OKC_;
        if (kc) __syncthreads();
#pragma unroll
        for (int n = 0; n < 3; n++) {
            int e = t + n * 256;                     // < 768
            int ocl = e / 24, kq = e % 24;
            uint2 v = make_uint2(0u, 0u);
            if (ocl < 27)
                v = *reinterpret_cast<const uint2*>(wob + (size_t)ocl * CK_ + j0 + kq * 4);
            *reinterpret_cast<uint2*>(&s_w[ocl * OPITCH_ + kq * 4]) = v;
        }
        union { unsigned short s[24]; uint4 q[3]; } pk;
#pragma unroll
        for (int m = 0; m < 24; m++) {
            int jg = j0 + jlb + m;
            int c  = (jg * 7282) >> 16;              // jg/9
            int k  = jg - 9 * c;
            int yy = h + k / 3 - 1, xx = w + k % 3 - 1;
            bool ok = ((unsigned)yy < HH_) & ((unsigned)xx < WW_);
            float v = ok ? xb[(size_t)c * HW_ + yy * WW_ + xx] : 0.f;
            pk.s[m] = f2bf(v);
        }
        {
            uint4* dst = reinterpret_cast<uint4*>(&s_cols[i * OPITCH_ + jlb]);
            dst[0] = pk.q[0]; dst[1] = pk.q[1]; dst[2] = pk.q[2];
        }
        __syncthreads();
#pragma unroll
        for (int ks = 0; ks < OKC_ / 32; ks++) {
            short8 a0 = *reinterpret_cast<const short8*>(
                &s_w[(l15) * OPITCH_ + ks * 32 + quad * 8]);
            short8 a1 = *reinterpret_cast<const short8*>(
                &s_w[(16 + l15) * OPITCH_ + ks * 32 + quad * 8]);
            short8 b0 = *reinterpret_cast<const short8*>(
                &s_cols[(wave * 16 + l15) * OPITCH_ + ks * 32 + quad * 8]);
            acc[0] = __builtin_amdgcn_mfma_f32_16x16x32_bf16(a0, b0, acc[0], 0, 0, 0);
            acc[1] = __builtin_amdgcn_mfma_f32_16x16x32_bf16(a1, b0, acc[1], 0, 0, 0);
        }
    }

#pragma unroll
    for (int mt = 0; mt < 2; mt++) {
#pragma unroll
        for (int r = 0; r < 4; r++) {
            int oc = mt * 16 + quad * 4 + r;
            if (oc < 27) {
                int pix = p0 + wave * 16 + l15;
                om[((size_t)b * 27 + oc) * HW_ + pix] = acc[mt][r] + bo[oc];
            }
        }
    }
}

// ---------------------------------------------------------------------------
// Kernel 2: fused channels-last gather + bf16 MFMA GEMM.
//   Block: 256 oc x 64 px, 576 blocks. Chunk kc (36 total) = tap k = kc>>2,
//   channels c0 = (kc&3)*64. B-stage gathers 64px x 64ch coalesced from xt.
//   A/B XOR-swizzled pitch-64 LDS; MFMA/epilogue = R3-proven.
// ---------------------------------------------------------------------------
__global__ __launch_bounds__(256, 3) void deform_fused(
    const float* __restrict__ xt, const float* __restrict__ om,
    const unsigned short* __restrict__ wb, const float* __restrict__ bconv,
    float* __restrict__ outb)
{
    __shared__ __align__(16) unsigned short sA[CHO_ * 64];   // 32768 B (swizzled)
    __shared__ __align__(16) unsigned short sB[64 * 64];     //  8192 B (swizzled)
    __shared__ float s_py[KK_ * 64], s_px[KK_ * 64], s_mask[KK_ * 64]; // 6912 B

    const int t = threadIdx.x;
    // XCD-aware bijective remap: 576 = 8 XCDs x 72 contiguous units
    const int bid = blockIdx.x;
    const int j   = (bid & 7) * 72 + (bid >> 3);     // [0,576)
    const int pixtile = j % 144;
    const int b       = j / 144;
    const int p0 = pixtile * 64;

    // ---- meta: py/px/mask for 9 taps x 64 pixels (once per block) ----
    for (int e = t; e < KK_ * 64; e += 256) {
        int k = e >> 6, i = e & 63;
        int p = p0 + i;
        int h = p / WW_, w = p % WW_;
        const float* omb = om + ((size_t)b * 27) * HW_ + p;
        float dy = omb[(2 * k) * HW_];
        float dx = omb[(2 * k + 1) * HW_];
        float m  = omb[(18 + k) * HW_];
        s_py[e]   = dy + (float)(h + k / 3 - 1);
        s_px[e]   = dx + (float)(w + (k % 3) - 1);
        s_mask[e] = 1.f / (1.f + __expf(-m));
    }

    const int lane = t & 63, wave = t >> 6;
    const int quad = lane >> 4, l15 = lane & 15;
    const int pxl  = t >> 2;           // gather role: pixel 0..63
    const int cg   = t & 3;            // gather role: 16-ch group

    f32x4 acc[4][4];
#pragma unroll
    for (int m = 0; m < 4; m++)
#pragma unroll
        for (int n = 0; n < 4; n++)
            acc[m][n] = (f32x4){0.f, 0.f, 0.f, 0.f};

    const float* xtb = xt + (size_t)b * HW_ * CHI_;
    char* sAb = (char*)sA;
    char* sBb = (char*)sB;

    __syncthreads();   // meta visible

    for (int kc = 0; kc < 36; kc++) {
        const int j0 = kc * 64;
        if (kc) __syncthreads();
        // ---- stage A (W'): 256 oc x 64 kk, 8 x uint4 per thread, swizzled
#pragma unroll
        for (int n = 0; n < 8; n++) {
            int e = t + n * 256;                   // < 2048
            int ocl = e >> 3, ko = e & 7;
            uint4 v = *reinterpret_cast<const uint4*>(
                wb + (size_t)ocl * CK_ + j0 + ko * 8);
            *reinterpret_cast<uint4*>(
                sAb + (ocl << 7) + ((ko << 4) ^ ((ocl & 7) << 4))) = v;
        }
        // ---- stage B: gather 64 px x 64 ch for tap k (coalesced) ----
        {
            const int k  = kc >> 2;
            const int c0 = (kc & 3) << 6;
            const int e  = k * 64 + pxl;
            float py = s_py[e], pxx = s_px[e], msk = s_mask[e];
            float y0f = floorf(py), x0f = floorf(pxx);
            float ly = py - y0f, lx = pxx - x0f;
            int y0 = (int)y0f, x0 = (int)x0f;
            float vy0 = ((unsigned)y0       < HH_) ? 1.f : 0.f;
            float vy1 = ((unsigned)(y0 + 1) < HH_) ? 1.f : 0.f;
            float vx0 = ((unsigned)x0       < WW_) ? 1.f : 0.f;
            float vx1 = ((unsigned)(x0 + 1) < WW_) ? 1.f : 0.f;
            int yc0 = min(max(y0, 0), HH_ - 1), yc1 = min(max(y0 + 1, 0), HH_ - 1);
            int xc0 = min(max(x0, 0), WW_ - 1), xc1 = min(max(x0 + 1, 0), WW_ - 1);
            float wy0 = 1.f - ly, wx0 = 1.f - lx;
            float w00 = wy0 * wx0 * vy0 * vx0 * msk;
            float w01 = wy0 * lx  * vy0 * vx1 * msk;
            float w10 = ly  * wx0 * vy1 * vx0 * msk;
            float w11 = ly  * lx  * vy1 * vx1 * msk;
            const float* base = xtb + c0 + cg * 16;
            const float4* r00 = reinterpret_cast<const float4*>(
                base + (size_t)(yc0 * WW_ + xc0) * CHI_);
            const float4* r01 = reinterpret_cast<const float4*>(
                base + (size_t)(yc0 * WW_ + xc1) * CHI_);
            const float4* r10 = reinterpret_cast<const float4*>(
                base + (size_t)(yc1 * WW_ + xc0) * CHI_);
            const float4* r11 = reinterpret_cast<const float4*>(
                base + (size_t)(yc1 * WW_ + xc1) * CHI_);
            union { unsigned short s[16]; uint4 q[2]; } pk;
#pragma unroll
            for (int i = 0; i < 4; i++) {
                float4 fa = r00[i], fb = r01[i], fc = r10[i], fd = r11[i];
                pk.s[i * 4 + 0] = f2bf(fa.x * w00 + fb.x * w01 + fc.x * w10 + fd.x * w11);
                pk.s[i * 4 + 1] = f2bf(fa.y * w00 + fb.y * w01 + fc.y * w10 + fd.y * w11);
                pk.s[i * 4 + 2] = f2bf(fa.z * w00 + fb.z * w01 + fc.z * w10 + fd.z * w11);
                pk.s[i * 4 + 3] = f2bf(fa.w * w00 + fb.w * w01 + fc.w * w10 + fd.w * w11);
            }
            const int u0 = cg << 1;                // 16B-unit col index
            *reinterpret_cast<uint4*>(
                sBb + (pxl << 7) + ((u0 << 4) ^ ((pxl & 7) << 4))) = pk.q[0];
            *reinterpret_cast<uint4*>(
                sBb + (pxl << 7) + (((u0 + 1) << 4) ^ ((pxl & 7) << 4))) = pk.q[1];
        }
        __syncthreads();
        // ---- MFMA: 2 K-steps of 32; wave = 64-oc slice, full 64 px ----
#pragma unroll
        for (int ks = 0; ks < 2; ks++) {
            short8 afr[4], bfr[4];
#pragma unroll
            for (int m = 0; m < 4; m++) {
                int r = wave * 64 + m * 16 + l15;
                afr[m] = *reinterpret_cast<const short8*>(
                    sAb + (r << 7) + (((ks << 6) + (quad << 4)) ^ ((r & 7) << 4)));
            }
#pragma unroll
            for (int n = 0; n < 4; n++) {
                int r = n * 16 + l15;
                bfr[n] = *reinterpret_cast<const short8*>(
                    sBb + (r << 7) + (((ks << 6) + (quad << 4)) ^ ((r & 7) << 4)));
            }
#pragma unroll
            for (int m = 0; m < 4; m++)
#pragma unroll
                for (int n = 0; n < 4; n++)
                    acc[m][n] = __builtin_amdgcn_mfma_f32_16x16x32_bf16(
                        afr[m], bfr[n], acc[m][n], 0, 0, 0);
        }
    }

    // ---- epilogue: C/D layout col=lane&15 (pixel), row=quad*4+r (oc) ----
#pragma unroll
    for (int m = 0; m < 4; m++) {
#pragma unroll
        for (int n = 0; n < 4; n++) {
#pragma unroll
            for (int r = 0; r < 4; r++) {
                int oc  = wave * 64 + m * 16 + quad * 4 + r;
                int pix = p0 + n * 16 + l15;
                outb[((size_t)b * CHO_ + oc) * HW_ + pix] = acc[m][n][r] + bconv[oc];
            }
        }
    }
}

// ---------------------------------------------------------------------------
// Kernel 3: BN statistics (sum, sumsq) per channel, deterministic two-pass
// ---------------------------------------------------------------------------
__global__ __launch_bounds__(256) void bn_stats(
    const float* __restrict__ outb, float* __restrict__ stats)
{
    int o = blockIdx.x, t = threadIdx.x;
    float s = 0.f, s2 = 0.f;
    for (int b = 0; b < BN_; b++) {
        const float* base = outb + ((size_t)b * CHO_ + o) * HW_;
        for (int p = t; p < HW_; p += 256) {
            float v = base[p];
            s += v; s2 += v * v;
        }
    }
#pragma unroll
    for (int off = 32; off > 0; off >>= 1) {
        s  += __shfl_down(s,  off, 64);
        s2 += __shfl_down(s2, off, 64);
    }
    __shared__ float rs[4], rs2[4];
    int lane = t & 63, wv = t >> 6;
    if (lane == 0) { rs[wv] = s; rs2[wv] = s2; }
    __syncthreads();
    if (t == 0) {
        stats[o]        = rs[0] + rs[1] + rs[2] + rs[3];
        stats[CHO_ + o] = rs2[0] + rs2[1] + rs2[2] + rs2[3];
    }
}

// ---------------------------------------------------------------------------
// Kernel 4: BN apply + ReLU, f32 out
// ---------------------------------------------------------------------------
__global__ __launch_bounds__(256) void bn_apply(
    const float* __restrict__ outb, const float* __restrict__ stats,
    const float* __restrict__ gamma, const float* __restrict__ beta,
    float* __restrict__ y)
{
    int idx = blockIdx.x * 256 + threadIdx.x;
    size_t i0 = (size_t)idx * 4;                  // < 9437184
    int o = (int)((i0 / HW_) % CHO_);
    float4 v = *reinterpret_cast<const float4*>(outb + i0);
    const float invN = 1.f / (float)NRED_;
    float mu  = stats[o] * invN;
    float var = stats[CHO_ + o] * invN - mu * mu;
    float inv = rsqrtf(var + BN_EPS_);
    float sc = gamma[o] * inv;
    float sh = beta[o] - mu * sc;
    float4 r;
    r.x = fmaxf(v.x * sc + sh, 0.f);
    r.y = fmaxf(v.y * sc + sh, 0.f);
    r.z = fmaxf(v.z * sc + sh, 0.f);
    r.w = fmaxf(v.w * sc + sh, 0.f);
    *reinterpret_cast<float4*>(y + i0) = r;
}

// ---------------------------------------------------------------------------
extern "C" void kernel_launch(void* const* d_in, const int* in_sizes, int n_in,
                              void* d_out, int out_size, void* d_ws, size_t ws_size,
                              hipStream_t stream)
{
    const float* x   = (const float*)d_in[0];
    const float* wof = (const float*)d_in[1];
    const float* bof = (const float*)d_in[2];
    const float* wcv = (const float*)d_in[3];
    const float* bcv = (const float*)d_in[4];
    const float* gam = (const float*)d_in[5];
    const float* bet = (const float*)d_in[6];
    float* y = (float*)d_out;

    char* ws = (char*)d_ws;
    float*          om    = (float*)ws;                                   // 3.98 MB
    float*          outb  = (float*)(ws + (size_t)4 * 1024 * 1024);       // 36 MB
    float*          stats = (float*)(ws + (size_t)40 * 1024 * 1024);      // 2 KB
    unsigned short* wbf2  = (unsigned short*)(ws + (size_t)40 * 1024 * 1024 + 8192);            // 1.125 MB
    unsigned short* wob   = (unsigned short*)(ws + (size_t)40 * 1024 * 1024 + 8192 + 1179648);  // 121.5 KB
    float*          xt    = (float*)(ws + (size_t)44 * 1024 * 1024);      // 37.75 MB

    w2b_perm<<<(CHO_ * CK_) / 256, 256, 0, stream>>>(wcv, wbf2);  // 2304 blocks
    w2b<<<(27 * CK_) / 256, 256, 0, stream>>>(wof, wob);          // 243 blocks
    transpose_x<<<BN_ * 144 * 4, 256, 0, stream>>>(x, xt);        // 2304 blocks
    offset_mfma<<<BN_ * (HW_ / OTPX_), 256, 0, stream>>>(x, wob, bof, om);
    deform_fused<<<BN_ * (HW_ / 64), 256, 0, stream>>>(xt, om, wbf2, bcv, outb);
    bn_stats<<<CHO_, 256, 0, stream>>>(outb, stats);
    bn_apply<<<(BN_ * CHO_ * HW_) / (4 * 256), 256, 0, stream>>>(outb, stats, gam, bet, y);
}